// Round 8
// baseline (203.511 us; speedup 1.0000x reference)
//
#include <hip/hip_runtime.h>
#include <math.h>

#define N_ANT 64
#define BATCH 131072
#define NSTEPS 63      // 31 internal softmax units + 32 leaf groups, DFS preorder
#define TPB 256        // 4 waves; each wave owns 2 m-tiles of 16 rows = 32 rows
#define RPB 128        // rows per block
#define PSTRIDE 126    // p-buffer row stride (floats): units 0..62 at offs 0..125
#define OSTRIDE 72     // po row stride (floats): 16B-aligned rows, b128-friendly

typedef float f32x4 __attribute__((ext_vector_type(4)));
typedef float v2f   __attribute__((ext_vector_type(2)));
typedef _Float16 f16x8 __attribute__((ext_vector_type(8)));

static __device__ __forceinline__ float fast_rcp(float x) {
#if __has_builtin(__builtin_amdgcn_rcpf)
    return __builtin_amdgcn_rcpf(x);
#else
    return 1.0f / x;
#endif
}

static __device__ __forceinline__ float dpp_xor1(float v) {  // quad_perm [1,0,3,2]
    return __int_as_float(__builtin_amdgcn_update_dpp(
        0, __float_as_int(v), 0xB1, 0xF, 0xF, true));
}
static __device__ __forceinline__ float dpp_xor2(float v) {  // quad_perm [2,3,0,1]
    return __int_as_float(__builtin_amdgcn_update_dpp(
        0, __float_as_int(v), 0x4E, 0xF, 0xF, true));
}

// Advance DFS-preorder state over the complete binary tree.
static __device__ __forceinline__ void dfs_next(int& l, int& n) {
    if (l < 5) { l = l + 1; n = 2 * n; }
    else {
        while (n & 1) { n >>= 1; l--; }
        n += 1;
    }
}

// Build B operand (128 K x 256 N real, N 252..255 zero-padded) as TWO fp16
// splits (B = B1 + B2 to ~2^-22), prepacked in MFMA B-fragment order:
//   slot t = ((ntile*4 + kstep)*64 + lane), 8 contiguous fp16 per slot,
//   element j -> B[k = kstep*32 + (lane>>4)*8 + j][n = ntile*16 + (lane&15)].
// Real col n=2c -> [wr ; -wi], n=2c+1 -> [wi ; wr]; unit s = c>>1 in DFS order.
__global__ void fill_B(const float* __restrict__ t0, const float* __restrict__ t1,
                       const float* __restrict__ t2, const float* __restrict__ t3,
                       const float* __restrict__ t4,
                       _Float16* __restrict__ B1p, _Float16* __restrict__ B2p) {
    const int t = blockIdx.x * 256 + threadIdx.x;   // 0..4095
    const int L = t & 63;
    const int kstep = (t >> 6) & 3;
    const int ntile = t >> 8;
    const int n = ntile * 16 + (L & 15);
    const int kbase = kstep * 32 + (L >> 4) * 8;

    f16x8 h1 = {0,0,0,0,0,0,0,0}, h2 = {0,0,0,0,0,0,0,0};
    if (n < 252) {
        const int c = n >> 1, part = n & 1;
        const int s = c >> 1, kidx = c & 1;
        int l = 0, nn = 0;
        for (int i = 0; i < s; ++i) dfs_next(l, nn);
#pragma unroll
        for (int j = 0; j < 8; ++j) {
            const int k = kbase + j;
            const int a = k & 63;       // antenna
            const int hi = k >> 6;      // 0: real-part rows, 1: imag-part rows
            float wr, wi;
            if (l < 5) {
                const float* th = (l == 0) ? t0 : (l == 1) ? t1 : (l == 2) ? t2
                                 : (l == 3) ? t3 : t4;
                float theta = th[(nn * N_ANT + a) * 2 + kidx];
                float sn, cs;
                sincosf(theta, &sn, &cs);
                wr = cs * 0.125f; wi = sn * 0.125f;
            } else {
                const int b = 2 * nn + kidx;
                const double step = (cos(M_PI - 1e-6) - 1.0) / 63.0;
                double cosaz = 1.0 + (double)b * step;
                double ph = M_PI * (double)a * cosaz;
                wr = (float)(cos(ph) * 0.125);
                wi = (float)(sin(ph) * 0.125);
            }
            float v = (part == 0) ? (hi == 0 ? wr : -wi)
                                  : (hi == 0 ? wi :  wr);
            _Float16 v1 = (_Float16)v;
            _Float16 v2 = (_Float16)(v - (float)v1);
            h1[j] = v1; h2[j] = v2;
        }
    }
    *(f16x8*)(B1p + (size_t)t * 8) = h1;
    *(f16x8*)(B2p + (size_t)t * 8) = h2;
}

__global__ __launch_bounds__(TPB, 2) void beam_mfma(const float* __restrict__ x,
                                                    const _Float16* __restrict__ B1p,
                                                    const _Float16* __restrict__ B2p,
                                                    float* __restrict__ out) {
    // Phase A: smem = B fragment buffer (64 KB, one split at a time).
    // Phase B (after final pass barrier): per-wave 16 KB region: p-buffer
    // (16 x PSTRIDE = 8064 B) at +0, po (16 x OSTRIDE = 4608 B) at +8192.
    __shared__ char smem[65536];
    _Float16* Bs = (_Float16*)smem;

    const int tid = threadIdx.x;
    const int wave = tid >> 6;
    const int L = tid & 63;

    float* pw = (float*)(smem + wave * 16384);
    float* ow = (float*)(smem + wave * 16384 + 8192);

    // ---- A fragments, 2 m-tiles per wave, fp16 split x = a1 + a2.
    const int rbase = blockIdx.x * RPB;
    f16x8 a1[2][4], a2[2][4];
#pragma unroll
    for (int mt = 0; mt < 2; ++mt) {
        const int arow = rbase + mt * 64 + wave * 16 + (L & 15);
        const float* xrow = x + (size_t)arow * 128;
#pragma unroll
        for (int ks = 0; ks < 4; ++ks) {
            const int kb = ks * 32 + (L >> 4) * 8;
            float4 u = *(const float4*)(xrow + kb);
            float4 v = *(const float4*)(xrow + kb + 4);
            float xv[8] = {u.x, u.y, u.z, u.w, v.x, v.y, v.z, v.w};
#pragma unroll
            for (int j = 0; j < 8; ++j) {
                _Float16 p = (_Float16)xv[j];
                a1[mt][ks][j] = p;
                a2[mt][ks][j] = (_Float16)(xv[j] - (float)p);
            }
        }
    }

    f32x4 acc[16][2];
#pragma unroll
    for (int nt = 0; nt < 16; ++nt) {
        acc[nt][0] = (f32x4){0.f, 0.f, 0.f, 0.f};
        acc[nt][1] = (f32x4){0.f, 0.f, 0.f, 0.f};
    }

    // ---- Stage B1; terms A1*B1 and A2*B1 (each frag read feeds 4 MFMAs).
    {
        const float4* src = (const float4*)B1p;
        float4* dst = (float4*)smem;
#pragma unroll
        for (int i = 0; i < 16; ++i) dst[i * TPB + tid] = src[i * TPB + tid];
    }
    __syncthreads();
#pragma unroll
    for (int nt = 0; nt < 16; ++nt) {
#pragma unroll
        for (int ks = 0; ks < 4; ++ks) {
            f16x8 b = *(const f16x8*)(Bs + (size_t)((nt * 4 + ks) * 64 + L) * 8);
            acc[nt][0] = __builtin_amdgcn_mfma_f32_16x16x32_f16(a1[0][ks], b, acc[nt][0], 0, 0, 0);
            acc[nt][1] = __builtin_amdgcn_mfma_f32_16x16x32_f16(a1[1][ks], b, acc[nt][1], 0, 0, 0);
            acc[nt][0] = __builtin_amdgcn_mfma_f32_16x16x32_f16(a2[0][ks], b, acc[nt][0], 0, 0, 0);
            acc[nt][1] = __builtin_amdgcn_mfma_f32_16x16x32_f16(a2[1][ks], b, acc[nt][1], 0, 0, 0);
        }
    }
    __syncthreads();

    // ---- Stage B2; term A1*B2.
    {
        const float4* src = (const float4*)B2p;
        float4* dst = (float4*)smem;
#pragma unroll
        for (int i = 0; i < 16; ++i) dst[i * TPB + tid] = src[i * TPB + tid];
    }
    __syncthreads();
#pragma unroll
    for (int nt = 0; nt < 16; ++nt) {
#pragma unroll
        for (int ks = 0; ks < 4; ++ks) {
            f16x8 b = *(const f16x8*)(Bs + (size_t)((nt * 4 + ks) * 64 + L) * 8);
            acc[nt][0] = __builtin_amdgcn_mfma_f32_16x16x32_f16(a1[0][ks], b, acc[nt][0], 0, 0, 0);
            acc[nt][1] = __builtin_amdgcn_mfma_f32_16x16x32_f16(a1[1][ks], b, acc[nt][1], 0, 0, 0);
        }
    }
    __syncthreads();   // all waves done with Bs before p/po overlay

    // ---- Wave-private epilogue per m-tile: no block barriers.
#pragma unroll
    for (int mt = 0; mt < 2; ++mt) {
        // Softmax p per complex col, in-register via DPP.
        // C layout: row = (L>>4)*4 + r, real col = nt*16 + (L&15).
#pragma unroll
        for (int nt = 0; nt < 16; ++nt) {
#pragma unroll
            for (int r = 0; r < 4; ++r) {
                float y  = acc[nt][mt][r];
                float yo = dpp_xor1(y);
                float g  = fmaf(y, y, yo * yo);       // gain of own complex col
                float gs = dpp_xor2(g);               // sibling col's gain
                float m  = fmaxf(g, gs);              // symmetric within pair
                float e  = __expf(g - m);
                float es = dpp_xor2(e);               // sibling's exp, shared
                float p  = e * fast_rcp(e + es);
                float ps = dpp_xor2(p);
                const int unit = nt * 4 + ((L & 15) >> 2);
                // unit==63 is the zero-padded cols 252..255: writing it would
                // land at offset 126 = NEXT row's unit 0 (root) -> R7 bug.
                if ((L & 3) == 0 && unit < NSTEPS) {  // one lane per (row, unit)
                    const int row  = (L >> 4) * 4 + r;
                    *(v2f*)(pw + row * PSTRIDE + unit * 2) = (v2f){p, ps};
                }
            }
        }
        __builtin_amdgcn_wave_barrier();  // keep ds_write -> ds_read order

        // Tree cascade: lane t handles row t (16 lanes), register DFS stack.
        if (L < 16) {
            const float* pr = pw + L * PSTRIDE;
            float* orow = ow + L * OSTRIDE;
            float stk[10];
            int l = 0, n = 0, gi = 0;
#pragma unroll
            for (int s = 0; s < NSTEPS; ++s) {
                v2f pp = *(const v2f*)(pr + 2 * s);
                float pme = (l == 0) ? 1.0f : stk[(l - 1) * 2 + (n & 1)];
                if (l < 5) {
                    stk[l * 2 + 0] = pme * pp.x;
                    stk[l * 2 + 1] = pme * pp.y;
                } else {
                    *(v2f*)(orow + 2 * gi) = (v2f){pme * pp.x, pme * pp.y};
                    gi++;
                }
                dfs_next(l, n);
            }
        }
        __builtin_amdgcn_wave_barrier();

        // Coalesced flush: wave's 16 rows x 64 floats = 4 KB contiguous.
        float4* ob = (float4*)(out + (size_t)(rbase + mt * 64 + wave * 16) * 64);
#pragma unroll
        for (int q = 0; q < 4; ++q) {
            const int f = q * 64 + L;
            const int row = f >> 4;
            const int col = (f & 15) * 4;
            ob[f] = *(const float4*)(ow + row * OSTRIDE + col);
        }
        __builtin_amdgcn_wave_barrier();  // ow reuse safety for next mt
    }
}

extern "C" void kernel_launch(void* const* d_in, const int* in_sizes, int n_in,
                              void* d_out, int out_size, void* d_ws, size_t ws_size,
                              hipStream_t stream) {
    const float* x  = (const float*)d_in[0];
    const float* t0 = (const float*)d_in[1];
    const float* t1 = (const float*)d_in[2];
    const float* t2 = (const float*)d_in[3];
    const float* t3 = (const float*)d_in[4];
    const float* t4 = (const float*)d_in[5];
    _Float16* B1p = (_Float16*)d_ws;                      // 64 KB
    _Float16* B2p = (_Float16*)((char*)d_ws + 65536);     // 64 KB

    fill_B<<<dim3(16), dim3(256), 0, stream>>>(t0, t1, t2, t3, t4, B1p, B2p);
    beam_mfma<<<dim3(BATCH / RPB), dim3(TPB), 0, stream>>>(x, B1p, B2p, (float*)d_out);
}

// Round 9
// 142.140 us; speedup vs baseline: 1.4318x; 1.4318x over previous
//
#include <hip/hip_runtime.h>
#include <math.h>

#define N_ANT 64
#define BATCH 131072
#define NSTEPS 63      // 31 internal softmax units + 32 leaf groups, DFS preorder
#define TPB 1024       // 16 waves; wave w owns m-tile w (weight cols 16w..16w+15)
#define NBLK 256       // 1 block per CU, zero dispatch tail
#define EPR 32         // elems per round
#define ROUNDS 16      // 512 elems per block
#define PSTR 66        // p-buffer unit-row stride (floats): 32 elems*2 + 2 pad

typedef float f32x4 __attribute__((ext_vector_type(4)));
typedef float v2f   __attribute__((ext_vector_type(2)));
typedef _Float16 f16x8 __attribute__((ext_vector_type(8)));
typedef _Float16 f16x4 __attribute__((ext_vector_type(4)));

static __device__ __forceinline__ float fast_rcp(float x) {
#if __has_builtin(__builtin_amdgcn_rcpf)
    return __builtin_amdgcn_rcpf(x);
#else
    return 1.0f / x;
#endif
}

// Advance DFS-preorder state over the complete binary tree.
// Internal units: l=0..4 (node n at layer l). Leaf groups: l==5 (group n).
static __device__ __forceinline__ void dfs_next(int& l, int& n) {
    if (l < 5) { l = l + 1; n = 2 * n; }
    else {
        while (n & 1) { n >>= 1; l--; }
        n += 1;
    }
}

// Build W operand (252 M x 128 K real, M 252..255 zero-padded) as TWO fp16
// splits (W = W1 + W2 to ~2^-22), prepacked in MFMA A-fragment order:
//   slot t = ((mtile*4 + kstep)*64 + lane), 8 contiguous fp16 per slot,
//   element j -> W[m = mtile*16 + (lane&15)][k = kstep*32 + (lane>>4)*8 + j].
// Real row m=2c -> [wr ; -wi] over k, m=2c+1 -> [wi ; wr]; unit s = c>>1 DFS.
__global__ void fill_B(const float* __restrict__ t0, const float* __restrict__ t1,
                       const float* __restrict__ t2, const float* __restrict__ t3,
                       const float* __restrict__ t4,
                       _Float16* __restrict__ B1p, _Float16* __restrict__ B2p) {
    const int t = blockIdx.x * 256 + threadIdx.x;   // 0..4095
    const int L = t & 63;
    const int kstep = (t >> 6) & 3;
    const int ntile = t >> 8;
    const int n = ntile * 16 + (L & 15);
    const int kbase = kstep * 32 + (L >> 4) * 8;

    f16x8 h1 = {0,0,0,0,0,0,0,0}, h2 = {0,0,0,0,0,0,0,0};
    if (n < 252) {
        const int c = n >> 1, part = n & 1;
        const int s = c >> 1, kidx = c & 1;
        int l = 0, nn = 0;
        for (int i = 0; i < s; ++i) dfs_next(l, nn);
#pragma unroll
        for (int j = 0; j < 8; ++j) {
            const int k = kbase + j;
            const int a = k & 63;       // antenna
            const int hi = k >> 6;      // 0: real-part rows, 1: imag-part rows
            float wr, wi;
            if (l < 5) {
                const float* th = (l == 0) ? t0 : (l == 1) ? t1 : (l == 2) ? t2
                                 : (l == 3) ? t3 : t4;
                float theta = th[(nn * N_ANT + a) * 2 + kidx];
                float sn, cs;
                sincosf(theta, &sn, &cs);
                wr = cs * 0.125f; wi = sn * 0.125f;
            } else {
                const int b = 2 * nn + kidx;
                const double step = (cos(M_PI - 1e-6) - 1.0) / 63.0;
                double cosaz = 1.0 + (double)b * step;
                double ph = M_PI * (double)a * cosaz;
                wr = (float)(cos(ph) * 0.125);
                wi = (float)(sin(ph) * 0.125);
            }
            float v = (part == 0) ? (hi == 0 ? wr : -wi)
                                  : (hi == 0 ? wi :  wr);
            _Float16 v1 = (_Float16)v;
            _Float16 v2 = (_Float16)(v - (float)v1);
            h1[j] = v1; h2[j] = v2;
        }
    }
    *(f16x8*)(B1p + (size_t)t * 8) = h1;
    *(f16x8*)(B2p + (size_t)t * 8) = h2;
}

__global__ __launch_bounds__(TPB) void beam_mfma(const float* __restrict__ x,
                                                 const _Float16* __restrict__ W1p,
                                                 const _Float16* __restrict__ W2p,
                                                 float* __restrict__ out) {
    // x slice (32 elems x 128) as fp16, frag-swizzled, double-buffered (16 KB).
    __shared__ _Float16 xb[2][4096];
    // softmax pairs, u-major [64 units][PSTR], double-buffered (33.8 KB).
    __shared__ float pb[2][64 * PSTR];

    const int tid = threadIdx.x;
    const int w   = tid >> 6;     // wave = m-tile (units 4w..4w+3)
    const int L   = tid & 63;
    const int q   = L >> 4;
    const int e15 = L & 15;

    // ---- W fragments (A-operand) for m-tile w, both fp16 splits: 32 VGPRs.
    f16x8 w1f[4], w2f[4];
#pragma unroll
    for (int ks = 0; ks < 4; ++ks) {
        w1f[ks] = *(const f16x8*)(W1p + (size_t)((w * 4 + ks) * 64 + L) * 8);
        w2f[ks] = *(const f16x8*)(W2p + (size_t)((w * 4 + ks) * 64 + L) * 8);
    }

    // ---- Per-lane DFS metadata: lane u == DFS unit u in the tree phase.
    int myl = -1, myn = 0;
    {
        int cl = 0, cn = 0;
        for (int s = 0; s < NSTEPS; ++s) {
            if (s == L) { myl = cl; myn = cn; }
            dfs_next(cl, cn);
        }
    }
    // Leaf lane: DFS indices of its 5 internal ancestors + branch sides.
    const int sd0 = (myn >> 4) & 1, sd1 = (myn >> 3) & 1, sd2 = (myn >> 2) & 1,
              sd3 = (myn >> 1) & 1, sd4 = myn & 1;
    const int a0 = 0;
    const int a1 = a0 + 1 + sd0 * 31;   // subtree sizes 31,15,7,3
    const int a2 = a1 + 1 + sd1 * 15;
    const int a3 = a2 + 1 + sd2 * 7;
    const int a4 = a3 + 1 + sd3 * 3;

    // ---- Staging decode: thread handles 4 floats of the round's x slice.
    const int s_er = tid & 31;
    const int s_rt = tid >> 5;
    const int s_h  = s_rt & 1;
    const int s_q  = (s_rt >> 1) & 3;
    const int s_ks = s_rt >> 3;
    const int s_goff = s_er * 128 + s_ks * 32 + s_q * 8 + s_h * 4;       // floats
    const int s_loff = ((s_ks * 4 + s_q) * 32 + s_er) * 8 + s_h * 4;    // halves

    const long base = (long)blockIdx.x * (EPR * ROUNDS);

    // Prologue: stage slice 0.
    {
        float4 v = *(const float4*)(x + base * 128 + s_goff);
        f16x4 hv = {(_Float16)v.x, (_Float16)v.y, (_Float16)v.z, (_Float16)v.w};
        *(f16x4*)(&xb[0][s_loff]) = hv;
    }
    __syncthreads();

#pragma unroll 1
    for (int r = 0; r < ROUNDS; ++r) {
        const int cur = r & 1;
        const bool more = (r + 1 < ROUNDS);
        // Prefetch next slice early (HBM latency hidden under MFMA phase).
        float4 nv = {0.f, 0.f, 0.f, 0.f};
        if (more) nv = *(const float4*)(x + (base + (long)(r + 1) * EPR) * 128 + s_goff);

        // ---- MFMA: C[wcol][elem], 2 elem-groups, 2 W-split terms.
        f32x4 acc0 = {0,0,0,0}, acc1 = {0,0,0,0};
#pragma unroll
        for (int ks = 0; ks < 4; ++ks) {
            const _Float16* xc = &xb[cur][(size_t)((ks * 4 + q) * 32) * 8];
            f16x8 b0 = *(const f16x8*)(xc + e15 * 8);
            f16x8 b1 = *(const f16x8*)(xc + (16 + e15) * 8);
            acc0 = __builtin_amdgcn_mfma_f32_16x16x32_f16(w1f[ks], b0, acc0, 0, 0, 0);
            acc1 = __builtin_amdgcn_mfma_f32_16x16x32_f16(w1f[ks], b1, acc1, 0, 0, 0);
            acc0 = __builtin_amdgcn_mfma_f32_16x16x32_f16(w2f[ks], b0, acc0, 0, 0, 0);
            acc1 = __builtin_amdgcn_mfma_f32_16x16x32_f16(w2f[ks], b1, acc1, 0, 0, 0);
        }

        // ---- Stage next slice (cvt once per chunk, shared by all 16 waves).
        if (more) {
            f16x4 hv = {(_Float16)nv.x, (_Float16)nv.y, (_Float16)nv.z, (_Float16)nv.w};
            *(f16x4*)(&xb[cur ^ 1][s_loff]) = hv;
        }

        // ---- Lane-local softmax: lane holds (re0,im0,re1,im1) of unit u, elem er.
        const int u = 4 * w + q;
#pragma unroll
        for (int g = 0; g < 2; ++g) {
            f32x4 a = g ? acc1 : acc0;
            float g0 = fmaf(a.x, a.x, a.y * a.y);
            float g1 = fmaf(a.z, a.z, a.w * a.w);
            float m  = fmaxf(g0, g1);
            float e0 = __expf(g0 - m);
            float e1 = __expf(g1 - m);
            float inv = fast_rcp(e0 + e1);
            if (u < NSTEPS)   // u==63 = zero-padded cols, must not write
                *(v2f*)(&pb[cur][u * PSTR + 2 * (g * 16 + e15)]) = (v2f){e0 * inv, e1 * inv};
        }
        __syncthreads();   // p(r) ready; xb[nxt] staged (barrier drains all)

        // ---- Tree: lane u = unit u; leaf lanes gather 5 ancestors via shfl,
        // write the elem's output pair directly to global (row fully covered
        // by the 32 leaf lanes -> 4 complete 64B lines per store instr).
#pragma unroll
        for (int pass = 0; pass < 2; ++pass) {
            const int er = 2 * w + pass;   // wave handles elems 2w, 2w+1
            v2f pp = *(const v2f*)(&pb[cur][L * PSTR + 2 * er]);
            float p0x = __shfl(pp.x, a0), p0y = __shfl(pp.y, a0);
            float p1x = __shfl(pp.x, a1), p1y = __shfl(pp.y, a1);
            float p2x = __shfl(pp.x, a2), p2y = __shfl(pp.y, a2);
            float p3x = __shfl(pp.x, a3), p3y = __shfl(pp.y, a3);
            float p4x = __shfl(pp.x, a4), p4y = __shfl(pp.y, a4);
            float P = (sd0 ? p0y : p0x) * (sd1 ? p1y : p1x) * (sd2 ? p2y : p2x)
                    * (sd3 ? p3y : p3x) * (sd4 ? p4y : p4x);
            if (myl == 5) {
                *(v2f*)(out + (base + (long)r * EPR + er) * 64 + 2 * myn) =
                    (v2f){P * pp.x, P * pp.y};
            }
        }
        // p(cur) reused only at round r+2, after everyone passed barrier(r+1).
    }
}

extern "C" void kernel_launch(void* const* d_in, const int* in_sizes, int n_in,
                              void* d_out, int out_size, void* d_ws, size_t ws_size,
                              hipStream_t stream) {
    const float* x  = (const float*)d_in[0];
    const float* t0 = (const float*)d_in[1];
    const float* t1 = (const float*)d_in[2];
    const float* t2 = (const float*)d_in[3];
    const float* t3 = (const float*)d_in[4];
    const float* t4 = (const float*)d_in[5];
    _Float16* W1p = (_Float16*)d_ws;                      // 64 KB
    _Float16* W2p = (_Float16*)((char*)d_ws + 65536);     // 64 KB

    fill_B<<<dim3(16), dim3(256), 0, stream>>>(t0, t1, t2, t3, t4, W1p, W2p);
    beam_mfma<<<dim3(NBLK), dim3(TPB), 0, stream>>>(x, W1p, W2p, (float*)d_out);
}